// Round 4
// baseline (89.824 us; speedup 1.0000x reference)
//
#include <hip/hip_runtime.h>
#include <math.h>

// Chamfer p-norm loss (P=5), B=8, N=M=4096, C=3.
// R12: kill the LDS pipe bottleneck. R11 evidence: doubling occupancy
// (4->8 waves/SIMD) left the kernel at 40us with VALUBusy 56% -> shared-
// resource-throughput-bound. Arithmetic: 8192 broadcast ds_read_b128/CU
// x ~12cyc = 41us = measured 40.2us. The per-split ref table is 4KB and
// every lane reads the same address — LDS staging is pure overhead
// (guide common-mistake #7). Change:
//  (a) tiny mktab kernel precomputes a pair-layout (x,x',y,y')(z,z',h,h')
//      table (1MB in ws); kernel boundary = cross-XCD visibility (R8-proven).
//  (b) scan reads the table with uniform-address loads (scalar pipe /
//      broadcast L1) — ZERO ds_read in the hot loop.
//  (c) f32x2 lanes repacked over the 2 refs of a pair (table-adjacent)
//      instead of 2 queries: operands feed v_pk_fma_f32 with no splats;
//      per-(q,r) fma chain bit-identical; min exact-commutative; strict-<
//      earliest-group tie-break + smallest-j rescan unchanged => absmax 0.
// R10/R11 lessons kept: NO __threadfence (per-wave L2 wb/inv = ~100us);
// __syncthreads' mandatory vmcnt(0) drains atomicMax before tid0's counter
// bump; consumers read tab/psum via AGENT-scope atomic loads (sc bypass).
// Counter init in poisoned ws: CANARY word (never written) holds the fill
// value; "last" test old==canary+(n-1); finalizer restores counters.

#define BQ      256
#define QPT     2             // queries per thread
#define SPLITS  16
#define CH      256           // refs per split-block
#define GS      8             // refs per tracked group
#define NG      (CH / GS)     // 32 groups
#define BIGOFF  64.0f         // folds into h: scores stay in (64-|q|^2/2, ~200) > 0
#define NQTOT   65536         // 2 dirs * 8 batches * 4096 queries
#define NTILE   128           // query tiles of 512
#define TILEQ   512           // queries per tile (BQ * QPT)

typedef float f32x2 __attribute__((ext_vector_type(2)));

static __device__ __forceinline__ f32x2 mk2(float s) { f32x2 v; v.x = s; v.y = s; return v; }
static __device__ __forceinline__ f32x2 fma2(f32x2 a, f32x2 b, f32x2 c) {
    return __builtin_elementwise_fma(a, b, c);
}
__device__ __forceinline__ unsigned int float_ord(float f) {
    unsigned int u = __float_as_uint(f);
    return (u & 0x80000000u) ? ~u : (u | 0x80000000u);
}

// ws layout (fast path):
//   [0,64)      legacy acc area (fallback path only)
//   [128,132)   CANARY u32 — never written; holds the uniform fill value
//   [192,196)   gcnt u32  — global tile-completion counter (starts at canary)
//   [256,768)   tcnt[128] u32 — per-tile split counters (start at canary)
//   [1024,1536) psum[128] f32 — per-tile partial sums
//   [4096, 4096+512K) tab u64[NQTOT] — complemented (score|j) keys, atomicMax
//   [1M, 2M)    tbl float4[2 dirs][8 b][2048 pairs][2] — pair-layout ref table
#define WS_ACC    0
#define WS_CANARY 128
#define WS_GCNT   192
#define WS_TCNT   256
#define WS_PSUM   1024
#define WS_TAB    4096
#define WS_TBL    1048576

// ---- phase 0: build the pair-layout (x,x',y,y')(z,z',h,h') ref table.
// 32768 pairs total = 2 dirs * 8 b * 2048 pairs. h chain bit-identical to
// the rescan's. Kernel-end release makes it visible to the scan (R8 pattern).
__global__ __launch_bounds__(BQ) void chamfer_mktab(
    const float* __restrict__ x, const float* __restrict__ y,
    float4* __restrict__ tbl)
{
    const int t   = blockIdx.x * BQ + threadIdx.x;   // 0..32767
    const int dir = t >> 14;
    const int b   = (t >> 11) & 7;
    const int pr  = t & 2047;
    const float* R = (dir == 0 ? y : x) + (size_t)b * 4096 * 3;
    const float* rp = R + (size_t)(2 * pr) * 3;
    const float f0 = rp[0], f1 = rp[1], f2 = rp[2];
    const float f3 = rp[3], f4 = rp[4], f5 = rp[5];
    const float h0 = fmaf(0.5f * f0, f0, fmaf(0.5f * f1, f1, fmaf(0.5f * f2, f2, BIGOFF)));
    const float h1 = fmaf(0.5f * f3, f3, fmaf(0.5f * f4, f4, fmaf(0.5f * f5, f5, BIGOFF)));
    const size_t o = ((size_t)(dir * 8 + b) * 2048 + pr) * 2;
    tbl[o]     = make_float4(f0, f3, f1, f4);
    tbl[o + 1] = make_float4(f2, f5, h0, h1);
}

// ---- fused scan + per-tile gather + finalize:
// grid = 128 query-tiles (512 q each) x 16 ref-splits = 2048 blocks
__global__ __launch_bounds__(BQ, 8) void chamfer_fused_r12(
    const float* __restrict__ x, const float* __restrict__ y,
    const float4* __restrict__ tbl,
    unsigned long long* __restrict__ tab,
    unsigned int* __restrict__ tcnt, unsigned int* __restrict__ gcnt,
    const unsigned int* __restrict__ canary_p,
    float* __restrict__ psum, float* __restrict__ out)
{
    __shared__ float red[4];
    __shared__ int s_flag;

    const int bid   = blockIdx.x;
    const int split = bid & (SPLITS - 1);
    const int tq    = bid >> 4;          // 0..127 = dir*64 + b*8 + t8
    const int dir   = tq >> 6;
    const int b     = (tq >> 3) & 7;
    const int t8    = tq & 7;

    const unsigned int canary = *canary_p;  // uniform fill value (0xAA.. or 0)

    const float* Q; const float* R;
    if (dir == 0) { Q = x + (size_t)b * 4096 * 3; R = y + (size_t)b * 4096 * 3; }
    else          { Q = y + (size_t)b * 4096 * 3; R = x + (size_t)b * 4096 * 3; }

    const int tid = threadIdx.x;

    // this block's split region of the table: 128 pairs = 256 float4s
    const float4* __restrict__ tb =
        tbl + ((size_t)(dir * 8 + b) * 4096 + (size_t)split * 256);

    // 2 scalar queries per thread: q0 = t8*512+tid, q1 = +256
    const int ql0 = t8 * TILEQ + tid;
    const int ql1 = ql0 + 256;
    const float qx0 = Q[ql0 * 3 + 0], qy0 = Q[ql0 * 3 + 1], qz0 = Q[ql0 * 3 + 2];
    const float qx1 = Q[ql1 * 3 + 0], qy1 = Q[ql1 * 3 + 1], qz1 = Q[ql1 * 3 + 2];
    // one-time splats for ref-packed pk math
    const f32x2 nqx0 = mk2(-qx0), nqy0 = mk2(-qy0), nqz0 = mk2(-qz0);
    const f32x2 nqx1 = mk2(-qx1), nqy1 = mk2(-qy1), nqz1 = mk2(-qz1);

    float best0 = 3.4e38f, best1 = 3.4e38f;
    int bg0 = 0, bg1 = 0;

    #pragma unroll 2
    for (int g = 0; g < NG; ++g) {
        float m0 = 3.4e38f, m1 = 3.4e38f;
        #pragma unroll
        for (int k = 0; k < GS / 2; ++k) {        // 4 ref-pairs per group
            const float4 a = tb[(g * 4 + k) * 2];       // rx0,rx1,ry0,ry1
            const float4 c = tb[(g * 4 + k) * 2 + 1];   // rz0,rz1,h0,h1
            f32x2 rx; rx.x = a.x; rx.y = a.y;
            f32x2 ry; ry.x = a.z; ry.y = a.w;
            f32x2 rz; rz.x = c.x; rz.y = c.y;
            f32x2 h2; h2.x = c.z; h2.y = c.w;
            // bit-identical chain: fma(nqx,rx, fma(nqy,ry, fma(nqz,rz,h)))
            const f32x2 s0 = fma2(nqx0, rx, fma2(nqy0, ry, fma2(nqz0, rz, h2)));
            const f32x2 s1 = fma2(nqx1, rx, fma2(nqy1, ry, fma2(nqz1, rz, h2)));
            m0 = fminf(fminf(m0, s0.x), s0.y);    // v_min3 candidate
            m1 = fminf(fminf(m1, s1.x), s1.y);
        }
        const bool c0 = m0 < best0;   // strict <: earliest group on ties
        best0 = c0 ? m0 : best0;  bg0 = c0 ? g : bg0;
        const bool c1 = m1 < best1;
        best1 = c1 ? m1 : best1;  bg1 = c1 ? g : bg1;
    }

    // exact index: re-scan winning GS-ref group from global R (L2-resident);
    // bit-identical fma/h chain reproduces the packed-path score exactly.
    #pragma unroll
    for (int hh = 0; hh < 2; ++hh) {
        const float bscore = hh ? best1 : best0;
        const int   bg     = hh ? bg1   : bg0;
        const float qx = hh ? qx1 : qx0;
        const float qy = hh ? qy1 : qy0;
        const float qz = hh ? qz1 : qz0;
        const int basej = split * CH + bg * GS;
        int bj = basej;
        #pragma unroll
        for (int j = GS - 1; j >= 0; --j) {      // descending: smallest j wins
            const float* rp = R + (size_t)(basej + j) * 3;
            const float rx = rp[0], ry = rp[1], rz = rp[2];
            const float h = fmaf(0.5f * rx, rx, fmaf(0.5f * ry, ry, fmaf(0.5f * rz, rz, BIGOFF)));
            const float s = fmaf(-qx, rx, fmaf(-qy, ry, fmaf(-qz, rz, h)));
            if (s == bscore) bj = basej + j;
        }
        const size_t qidx = (size_t)tq * TILEQ + hh * 256 + tid;
        // complemented key: max(~packed) == min(packed); 0xAA poison and
        // fresh zeros are both < any real key -> no init required.
        const unsigned long long key =
            ~(((unsigned long long)__float_as_uint(bscore) << 32) | (unsigned int)bj);
        atomicMax(&tab[qidx], key);   // fire-and-forget (return unused)
    }

    // ---- per-tile completion handshake: 16th split-block gathers the tile.
    // NO __threadfence (R9 lesson: per-wave buffer_wbl2/inv = ~100us).
    // __syncthreads' compiler-mandated s_waitcnt vmcnt(0) drains every
    // wave's atomicMax to the coherent point before tid0's counter bump.
    __syncthreads();
    if (tid == 0) {
        const unsigned int old = atomicAdd(&tcnt[tq], 1u);
        s_flag = (old == canary + (SPLITS - 1));
    }
    __syncthreads();
    if (!s_flag) return;

    // ---- gather this tile's 512 queries (2/thread). tab MUST be read with
    // AGENT-scope atomic loads (sc cache-bypass): local L2 may hold stale
    // poison lines; atomicMax updated the coherent point only (R4 lesson).
    float sthr = 0.0f;
    #pragma unroll
    for (int k = 0; k < QPT; ++k) {
        const int gq = tq * TILEQ + k * 256 + tid;
        const int q  = t8 * TILEQ + k * 256 + tid;
        const unsigned long long w =
            ~__hip_atomic_load(&tab[gq], __ATOMIC_RELAXED, __HIP_MEMORY_SCOPE_AGENT);
        const int j = (int)(unsigned int)w;
        const float dx = Q[q * 3 + 0] - R[(size_t)j * 3 + 0];
        const float dy = Q[q * 3 + 1] - R[(size_t)j * 3 + 1];
        const float dz = Q[q * 3 + 2] - R[(size_t)j * 3 + 2];
        const float ax = fabsf(dx), ay = fabsf(dy), az = fabsf(dz);
        const float ax2 = ax * ax, ay2 = ay * ay, az2 = az * az;
        sthr += ax2 * ax2 * ax + ay2 * ay2 * ay + az2 * az2 * az;
    }
    #pragma unroll
    for (int off = 32; off > 0; off >>= 1) sthr += __shfl_down(sthr, off, 64);
    const int wid = tid >> 6, lane = tid & 63;
    if (lane == 0) red[wid] = sthr;
    __syncthreads();

    if (tid == 0) {
        __hip_atomic_store(&psum[tq], red[0] + red[1] + red[2] + red[3],
                           __ATOMIC_RELAXED, __HIP_MEMORY_SCOPE_AGENT);
        // order psum store before gcnt bump: drain to coherent point (1 instr,
        // single thread — NOT a threadfence, no L2 writeback).
        asm volatile("s_waitcnt vmcnt(0)" ::: "memory");
        const unsigned int old = atomicAdd(gcnt, 1u);
        s_flag = (old == canary + (NTILE - 1));
    }
    __syncthreads();
    if (!s_flag) return;

    // ---- globally-last tile: finalize. x^0.2 via exp2/log2 (rel err ~1e-5).
    // psum read via AGENT-scope bypass loads: counter RMW return proved all
    // writers' stores performed at the coherent point before ours.
    if (tid < 64) {
        float v = 0.0f;
        if (tid < 16) {
            const int fb = tid >> 1, fdir = tid & 1;  // slot = b*2+dir
            float a = 0.0f;
            #pragma unroll
            for (int t = 0; t < 8; ++t)
                a += __hip_atomic_load(&psum[fdir * 64 + fb * 8 + t],
                                       __ATOMIC_RELAXED, __HIP_MEMORY_SCOPE_AGENT);
            v = exp2f(0.2f * log2f(a));
        }
        #pragma unroll
        for (int off = 8; off > 0; off >>= 1) v += __shfl_down(v, off, 64);
        if (tid == 0) out[0] = v * 0.125f;            // mean over B=8
    }
    // restore counters to the canary value so a non-repoisoned rerun is
    // still correct (tab is idempotent under atomicMax with same inputs).
    if (tid < NTILE)
        __hip_atomic_store(&tcnt[tid], canary, __ATOMIC_RELAXED, __HIP_MEMORY_SCOPE_AGENT);
    if (tid == 0)
        __hip_atomic_store(gcnt, canary, __ATOMIC_RELAXED, __HIP_MEMORY_SCOPE_AGENT);
}

// ================= round-2 proven fallback (generic sizes) =================
__global__ __launch_bounds__(BQ) void chamfer_nn_split_kernel(
    const float* __restrict__ x, const float* __restrict__ y,
    unsigned long long* __restrict__ packed, int N, int M)
{
    __shared__ float4 sref[1024];
    const int bid = blockIdx.x, split = bid & 3, qb = bid >> 2;
    const int tile = qb & 15, dir = (qb >> 4) & 1, b = qb >> 5;
    const float* Q; const float* R;
    if (dir == 0) { Q = x + (size_t)b * N * 3; R = y + (size_t)b * M * 3; }
    else          { Q = y + (size_t)b * M * 3; R = x + (size_t)b * N * 3; }
    const int tid = threadIdx.x, q = tile * BQ + tid, base = split * 1024;
    for (int j = tid; j < 1024; j += BQ) {
        const float rx = R[(size_t)(base + j) * 3 + 0];
        const float ry = R[(size_t)(base + j) * 3 + 1];
        const float rz = R[(size_t)(base + j) * 3 + 2];
        sref[j] = make_float4(rx, ry, rz, 0.5f * (rx * rx + ry * ry + rz * rz));
    }
    __syncthreads();
    const float qx = Q[q * 3 + 0], qy = Q[q * 3 + 1], qz = Q[q * 3 + 2];
    float best = 3.4e38f; int bestj = base;
    #pragma unroll 8
    for (int j = 0; j < 1024; ++j) {
        const float4 r = sref[j];
        float t = __fmaf_rn(-qx, r.x, r.w);
        t = __fmaf_rn(-qy, r.y, t);
        t = __fmaf_rn(-qz, r.z, t);
        const bool c = t < best;
        best = c ? t : best; bestj = c ? (base + j) : bestj;
    }
    const size_t idx = ((size_t)dir * 8 + b) * (size_t)N + q;
    atomicMin(&packed[idx], ((unsigned long long)float_ord(best) << 32) | (unsigned int)bestj);
}

__global__ __launch_bounds__(BQ) void chamfer_gather_kernel(
    const float* __restrict__ x, const float* __restrict__ y,
    const unsigned long long* __restrict__ packed,
    float* __restrict__ acc, int N, int M)
{
    __shared__ float red[4];
    const int tid = threadIdx.x;
    const size_t gq = (size_t)blockIdx.x * BQ + tid;
    const int dir = (int)(gq / ((size_t)8 * N));
    const size_t rem = gq - (size_t)dir * 8 * N;
    const int b = (int)(rem / N), q = (int)(rem - (size_t)b * N);
    const float* Q; const float* R;
    if (dir == 0) { Q = x + (size_t)b * N * 3; R = y + (size_t)b * M * 3; }
    else          { Q = y + (size_t)b * M * 3; R = x + (size_t)b * N * 3; }
    const int j = (int)(unsigned int)packed[gq];
    const float dx = Q[q * 3 + 0] - R[(size_t)j * 3 + 0];
    const float dy = Q[q * 3 + 1] - R[(size_t)j * 3 + 1];
    const float dz = Q[q * 3 + 2] - R[(size_t)j * 3 + 2];
    const float ax = fabsf(dx), ay = fabsf(dy), az = fabsf(dz);
    const float ax2 = ax * ax, ay2 = ay * ay, az2 = az * az;
    float s = ax2 * ax2 * ax + ay2 * ay2 * ay + az2 * az2 * az;
    #pragma unroll
    for (int off = 32; off > 0; off >>= 1) s += __shfl_down(s, off, 64);
    const int wid = tid >> 6, lane = tid & 63;
    if (lane == 0) red[wid] = s;
    __syncthreads();
    if (tid == 0) atomicAdd(&acc[b * 2 + dir], red[0] + red[1] + red[2] + red[3]);
}

__global__ void chamfer_finalize_kernel(const float* __restrict__ acc,
                                        float* __restrict__ out)
{
    if (threadIdx.x == 0 && blockIdx.x == 0) {
        float total = 0.0f;
        #pragma unroll
        for (int i = 0; i < 16; ++i) total += powf(acc[i], 0.2f);
        *out = total * 0.125f;
    }
}

extern "C" void kernel_launch(void* const* d_in, const int* in_sizes, int n_in,
                              void* d_out, int out_size, void* d_ws, size_t ws_size,
                              hipStream_t stream)
{
    const float* x = (const float*)d_in[0];
    const float* y = (const float*)d_in[1];
    float* out = (float*)d_out;
    const int N = in_sizes[0] / 24;  // B=8, C=3
    const int M = in_sizes[1] / 24;

    const size_t needed = WS_TBL + (size_t)32768 * 32;  // table ends at 2MB

    if (N == 4096 && M == 4096 && ws_size >= needed) {
        unsigned char* ws = (unsigned char*)d_ws;
        unsigned long long* tab = (unsigned long long*)(ws + WS_TAB);
        unsigned int* tcnt = (unsigned int*)(ws + WS_TCNT);
        unsigned int* gcnt = (unsigned int*)(ws + WS_GCNT);
        const unsigned int* canary = (const unsigned int*)(ws + WS_CANARY);
        float* psum = (float*)(ws + WS_PSUM);
        float4* tbl = (float4*)(ws + WS_TBL);
        chamfer_mktab<<<32768 / BQ, BQ, 0, stream>>>(x, y, tbl);
        chamfer_fused_r12<<<NTILE * SPLITS, BQ, 0, stream>>>(
            x, y, tbl, tab, tcnt, gcnt, canary, psum, out);
    } else {
        // round-2 proven path
        unsigned char* ws = (unsigned char*)d_ws;
        float* acc = (float*)ws;
        unsigned long long* ptab = (unsigned long long*)(ws + 4096);
        const size_t nQ = (size_t)2 * 8 * N;
        hipMemsetAsync(acc, 0, 64, stream);
        hipMemsetAsync(ptab, 0xFF, nQ * 8, stream);
        chamfer_nn_split_kernel<<<(int)(nQ / BQ) * 4, BQ, 0, stream>>>(x, y, ptab, N, M);
        chamfer_gather_kernel<<<(int)(nQ / BQ), BQ, 0, stream>>>(x, y, ptab, acc, N, M);
        chamfer_finalize_kernel<<<1, 64, 0, stream>>>(acc, out);
    }
}

// Round 6
// 87.868 us; speedup vs baseline: 1.0223x; 1.0223x over previous
//
#include <hip/hip_runtime.h>
#include <math.h>

// Chamfer p-norm loss (P=5), B=8, N=M=4096, C=3.
// R14 = R13 resubmit (R13 bench was an infra failure: "container failed
// twice", no counters). One hardening: the pipeline's final prefetch now
// wraps to group 0 ((g+2)&(NG-1), value never consumed) instead of
// over-reading one group past the table into ws slack — removes the
// ws_size-slack dependency. Everything else identical to R13.
//
// R13 theory: software-pipeline the ref-table reads + restore QPT=4.
// Evidence trail: R10(4w,LDS)~38-39, R11(8w,LDS)=40.2, R12(8w,table)=42.2 —
// three structures, same ~40us, VALU busy ~20us in all. Limiter is the
// 256 back-to-back load->use chains/thread (prefetch distance 0), not LDS,
// not occupancy. Changes vs R12:
//  (a) register double-buffer: prefetch group g+1 (8 x f32x4) while
//      computing group g (#pragma unroll 1 pins the pipeline).
//  (b) QPT 2->4 (R10's best shape): same 256 loads/thread, 2x compute per
//      load; grid 1024 blocks = 4/CU = 4 waves/SIMD (enough w/ prefetch).
//  (c) no repack movs: f32x4 buffers, pk operands via shufflevector
//      even-aligned aliases; queries kept only as negated splats (rescan
//      uses -nqx.x, bit-exact sign flip) -> VGPR ~115, bounds (256,4).
// R10/R11 lessons kept: NO __threadfence (per-wave L2 wb/inv = ~100us);
// __syncthreads' mandatory vmcnt(0) drains atomicMax before tid0's counter
// bump; consumers read tab/psum via AGENT-scope atomic loads (sc bypass).
// mktab->fused visibility = kernel boundary (R8-proven; implicit dispatch
// release/acquire). Counter init in poisoned ws: CANARY word (never
// written) holds the fill value; "last" test old==canary+(n-1); finalizer
// restores counters. Keys: complemented (score<<32|j), atomicMax.

#define BQ      256
#define QPT     4             // queries per thread
#define SPLITS  16
#define CH      256           // refs per split-block
#define GS      8             // refs per tracked group
#define NG      (CH / GS)     // 32 groups
#define BIGOFF  64.0f         // folds into h: scores stay in (64-|q|^2/2, ~200) > 0
#define NQTOT   65536         // 2 dirs * 8 batches * 4096 queries
#define NTILE   64            // query tiles of 1024
#define TILEQ   1024          // queries per tile (BQ * QPT)

typedef float f32x2 __attribute__((ext_vector_type(2)));
typedef float f32x4 __attribute__((ext_vector_type(4)));

static __device__ __forceinline__ f32x2 mk2(float s) { f32x2 v; v.x = s; v.y = s; return v; }
static __device__ __forceinline__ f32x2 fma2(f32x2 a, f32x2 b, f32x2 c) {
    return __builtin_elementwise_fma(a, b, c);
}
__device__ __forceinline__ unsigned int float_ord(float f) {
    unsigned int u = __float_as_uint(f);
    return (u & 0x80000000u) ? ~u : (u | 0x80000000u);
}

// ws layout (fast path):
//   [0,64)      legacy acc area (fallback path only)
//   [128,132)   CANARY u32 — never written; holds the uniform fill value
//   [192,196)   gcnt u32  — global tile-completion counter (starts at canary)
//   [256,512)   tcnt[64] u32 — per-tile split counters (start at canary)
//   [1024,1280) psum[64] f32 — per-tile partial sums
//   [4096, 4096+512K) tab u64[NQTOT] — complemented (score|j) keys, atomicMax
//   [1M, 2M)    tbl f32x4[2 dirs][8 b][2048 pairs][2] — pair-layout ref table
#define WS_ACC    0
#define WS_CANARY 128
#define WS_GCNT   192
#define WS_TCNT   256
#define WS_PSUM   1024
#define WS_TAB    4096
#define WS_TBL    1048576

// ---- phase 0: build the pair-layout (x,x',y,y')(z,z',h,h') ref table.
// 32768 pairs total = 2 dirs * 8 b * 2048 pairs. h chain bit-identical to
// the rescan's. Kernel-end release makes it visible to the scan (R8 pattern).
__global__ __launch_bounds__(BQ) void chamfer_mktab(
    const float* __restrict__ x, const float* __restrict__ y,
    float4* __restrict__ tbl)
{
    const int t   = blockIdx.x * BQ + threadIdx.x;   // 0..32767
    const int dir = t >> 14;
    const int b   = (t >> 11) & 7;
    const int pr  = t & 2047;
    const float* R = (dir == 0 ? y : x) + (size_t)b * 4096 * 3;
    const float* rp = R + (size_t)(2 * pr) * 3;
    const float f0 = rp[0], f1 = rp[1], f2 = rp[2];
    const float f3 = rp[3], f4 = rp[4], f5 = rp[5];
    const float h0 = fmaf(0.5f * f0, f0, fmaf(0.5f * f1, f1, fmaf(0.5f * f2, f2, BIGOFF)));
    const float h1 = fmaf(0.5f * f3, f3, fmaf(0.5f * f4, f4, fmaf(0.5f * f5, f5, BIGOFF)));
    const size_t o = ((size_t)(dir * 8 + b) * 2048 + pr) * 2;
    tbl[o]     = make_float4(f0, f3, f1, f4);
    tbl[o + 1] = make_float4(f2, f5, h0, h1);
}

// compute one GS-ref group (4 pairs) from a register buffer; bit-identical
// score chain; exact-commutative mins; strict-< earliest-group update.
#define COMPUTE_GROUP(BUF, G)                                              \
  {                                                                        \
    float mloc[QPT];                                                       \
    _Pragma("unroll")                                                      \
    for (int k4 = 0; k4 < 4; ++k4) {                                       \
      const f32x4 a = BUF[2 * k4];          /* rx0,rx1,ry0,ry1 */          \
      const f32x4 c = BUF[2 * k4 + 1];      /* rz0,rz1,h0,h1  */           \
      const f32x2 rx = __builtin_shufflevector(a, a, 0, 1);                \
      const f32x2 ry = __builtin_shufflevector(a, a, 2, 3);                \
      const f32x2 rz = __builtin_shufflevector(c, c, 0, 1);                \
      const f32x2 h2 = __builtin_shufflevector(c, c, 2, 3);                \
      _Pragma("unroll")                                                    \
      for (int qk = 0; qk < QPT; ++qk) {                                   \
        const f32x2 s = fma2(nqx[qk], rx,                                  \
                        fma2(nqy[qk], ry, fma2(nqz[qk], rz, h2)));         \
        if (k4 == 0) mloc[qk] = fminf(s.x, s.y);                           \
        else         mloc[qk] = fminf(fminf(mloc[qk], s.x), s.y);          \
      }                                                                    \
    }                                                                      \
    _Pragma("unroll")                                                      \
    for (int qk = 0; qk < QPT; ++qk) {                                     \
      const bool cc = mloc[qk] < best[qk];  /* strict <: earliest group */ \
      best[qk] = cc ? mloc[qk] : best[qk];                                 \
      bg[qk]   = cc ? (G) : bg[qk];                                        \
    }                                                                      \
  }

// ---- fused scan + per-tile gather + finalize:
// grid = 64 query-tiles (1024 q each) x 16 ref-splits = 1024 blocks
__global__ __launch_bounds__(BQ, 4) void chamfer_fused_r14(
    const float* __restrict__ x, const float* __restrict__ y,
    const f32x4* __restrict__ tbl,
    unsigned long long* __restrict__ tab,
    unsigned int* __restrict__ tcnt, unsigned int* __restrict__ gcnt,
    const unsigned int* __restrict__ canary_p,
    float* __restrict__ psum, float* __restrict__ out)
{
    __shared__ float red[4];
    __shared__ int s_flag;

    const int bid   = blockIdx.x;
    const int split = bid & (SPLITS - 1);
    const int tq    = bid >> 4;          // 0..63 = dir*32 + b*4 + t4
    const int dir   = tq >> 5;
    const int b     = (tq >> 2) & 7;
    const int t4    = tq & 3;

    const unsigned int canary = *canary_p;  // uniform fill value (0xAA.. or 0)

    const float* Q; const float* R;
    if (dir == 0) { Q = x + (size_t)b * 4096 * 3; R = y + (size_t)b * 4096 * 3; }
    else          { Q = y + (size_t)b * 4096 * 3; R = x + (size_t)b * 4096 * 3; }

    const int tid = threadIdx.x;

    // this block's split region of the table: 128 pairs = 256 f32x4s
    const f32x4* __restrict__ tb =
        tbl + ((size_t)(dir * 8 + b) * 4096 + (size_t)split * 256);

    // 4 scalar queries per thread, kept ONLY as negated pk splats
    // (rescan recovers q via bit-exact sign flip) — saves 12 VGPRs.
    f32x2 nqx[QPT], nqy[QPT], nqz[QPT];
    #pragma unroll
    for (int qk = 0; qk < QPT; ++qk) {
        const int ql = t4 * TILEQ + qk * 256 + tid;
        nqx[qk] = mk2(-Q[ql * 3 + 0]);
        nqy[qk] = mk2(-Q[ql * 3 + 1]);
        nqz[qk] = mk2(-Q[ql * 3 + 2]);
    }

    float best[QPT]; int bg[QPT];
    #pragma unroll
    for (int qk = 0; qk < QPT; ++qk) { best[qk] = 3.4e38f; bg[qk] = 0; }

    // ---- register double-buffered group pipeline:
    // prefetch group g+1 while computing g. Final prefetch wraps to group 0
    // ((g+2)&(NG-1)) — in-bounds, value never consumed (no ws over-read).
    f32x4 bufA[8], bufB[8];
    #pragma unroll
    for (int i = 0; i < 8; ++i) bufA[i] = tb[i];

    #pragma unroll 1
    for (int g = 0; g < NG; g += 2) {
        #pragma unroll
        for (int i = 0; i < 8; ++i) bufB[i] = tb[(g + 1) * 8 + i];
        COMPUTE_GROUP(bufA, g)
        const int gpre = (g + 2) & (NG - 1);   // wraps to 0 on last iter
        #pragma unroll
        for (int i = 0; i < 8; ++i) bufA[i] = tb[gpre * 8 + i];
        COMPUTE_GROUP(bufB, g + 1)
    }

    // exact index: re-scan winning GS-ref group from global R (L2-resident);
    // bit-identical fma/h chain reproduces the packed-path score exactly.
    #pragma unroll
    for (int qk = 0; qk < QPT; ++qk) {
        const float bscore = best[qk];
        const float qx = -nqx[qk].x;   // bit-exact double sign-flip
        const float qy = -nqy[qk].x;
        const float qz = -nqz[qk].x;
        const int basej = split * CH + bg[qk] * GS;
        int bj = basej;
        #pragma unroll
        for (int j = GS - 1; j >= 0; --j) {      // descending: smallest j wins
            const float* rp = R + (size_t)(basej + j) * 3;
            const float rx = rp[0], ry = rp[1], rz = rp[2];
            const float h = fmaf(0.5f * rx, rx, fmaf(0.5f * ry, ry, fmaf(0.5f * rz, rz, BIGOFF)));
            const float s = fmaf(-qx, rx, fmaf(-qy, ry, fmaf(-qz, rz, h)));
            if (s == bscore) bj = basej + j;
        }
        const size_t qidx = (size_t)tq * TILEQ + qk * 256 + tid;
        // complemented key: max(~packed) == min(packed); 0xAA poison and
        // fresh zeros are both < any real key -> no init required.
        const unsigned long long key =
            ~(((unsigned long long)__float_as_uint(bscore) << 32) | (unsigned int)bj);
        atomicMax(&tab[qidx], key);   // fire-and-forget (return unused)
    }

    // ---- per-tile completion handshake: 16th split-block gathers the tile.
    // NO __threadfence (R9 lesson: per-wave buffer_wbl2/inv = ~100us).
    // __syncthreads' compiler-mandated s_waitcnt vmcnt(0) drains every
    // wave's atomicMax to the coherent point before tid0's counter bump.
    __syncthreads();
    if (tid == 0) {
        const unsigned int old = atomicAdd(&tcnt[tq], 1u);
        s_flag = (old == canary + (SPLITS - 1));
    }
    __syncthreads();
    if (!s_flag) return;

    // ---- gather this tile's 1024 queries (4/thread). tab MUST be read with
    // AGENT-scope atomic loads (sc cache-bypass): local L2 may hold stale
    // poison lines; atomicMax updated the coherent point only (R4 lesson).
    float sthr = 0.0f;
    #pragma unroll
    for (int k = 0; k < QPT; ++k) {
        const int gq = tq * TILEQ + k * 256 + tid;
        const int q  = t4 * TILEQ + k * 256 + tid;
        const unsigned long long w =
            ~__hip_atomic_load(&tab[gq], __ATOMIC_RELAXED, __HIP_MEMORY_SCOPE_AGENT);
        const int j = (int)(unsigned int)w;
        const float dx = Q[q * 3 + 0] - R[(size_t)j * 3 + 0];
        const float dy = Q[q * 3 + 1] - R[(size_t)j * 3 + 1];
        const float dz = Q[q * 3 + 2] - R[(size_t)j * 3 + 2];
        const float ax = fabsf(dx), ay = fabsf(dy), az = fabsf(dz);
        const float ax2 = ax * ax, ay2 = ay * ay, az2 = az * az;
        sthr += ax2 * ax2 * ax + ay2 * ay2 * ay + az2 * az2 * az;
    }
    #pragma unroll
    for (int off = 32; off > 0; off >>= 1) sthr += __shfl_down(sthr, off, 64);
    const int wid = tid >> 6, lane = tid & 63;
    if (lane == 0) red[wid] = sthr;
    __syncthreads();

    if (tid == 0) {
        __hip_atomic_store(&psum[tq], red[0] + red[1] + red[2] + red[3],
                           __ATOMIC_RELAXED, __HIP_MEMORY_SCOPE_AGENT);
        // order psum store before gcnt bump: drain to coherent point (1 instr,
        // single thread — NOT a threadfence, no L2 writeback).
        asm volatile("s_waitcnt vmcnt(0)" ::: "memory");
        const unsigned int old = atomicAdd(gcnt, 1u);
        s_flag = (old == canary + (NTILE - 1));
    }
    __syncthreads();
    if (!s_flag) return;

    // ---- globally-last tile: finalize. x^0.2 via exp2/log2 (rel err ~1e-5).
    // psum read via AGENT-scope bypass loads: counter RMW return proved all
    // writers' stores performed at the coherent point before ours.
    if (tid < 64) {
        float v = 0.0f;
        if (tid < 16) {
            const int fb = tid >> 1, fdir = tid & 1;  // slot = b*2+dir
            float a = 0.0f;
            #pragma unroll
            for (int t = 0; t < 4; ++t)
                a += __hip_atomic_load(&psum[fdir * 32 + fb * 4 + t],
                                       __ATOMIC_RELAXED, __HIP_MEMORY_SCOPE_AGENT);
            v = exp2f(0.2f * log2f(a));
        }
        #pragma unroll
        for (int off = 8; off > 0; off >>= 1) v += __shfl_down(v, off, 64);
        if (tid == 0) out[0] = v * 0.125f;            // mean over B=8
    }
    // restore counters to the canary value so a non-repoisoned rerun is
    // still correct (tab is idempotent under atomicMax with same inputs).
    if (tid < NTILE)
        __hip_atomic_store(&tcnt[tid], canary, __ATOMIC_RELAXED, __HIP_MEMORY_SCOPE_AGENT);
    if (tid == 0)
        __hip_atomic_store(gcnt, canary, __ATOMIC_RELAXED, __HIP_MEMORY_SCOPE_AGENT);
}

// ================= round-2 proven fallback (generic sizes) =================
__global__ __launch_bounds__(BQ) void chamfer_nn_split_kernel(
    const float* __restrict__ x, const float* __restrict__ y,
    unsigned long long* __restrict__ packed, int N, int M)
{
    __shared__ float4 sref[1024];
    const int bid = blockIdx.x, split = bid & 3, qb = bid >> 2;
    const int tile = qb & 15, dir = (qb >> 4) & 1, b = qb >> 5;
    const float* Q; const float* R;
    if (dir == 0) { Q = x + (size_t)b * N * 3; R = y + (size_t)b * M * 3; }
    else          { Q = y + (size_t)b * M * 3; R = x + (size_t)b * N * 3; }
    const int tid = threadIdx.x, q = tile * BQ + tid, base = split * 1024;
    for (int j = tid; j < 1024; j += BQ) {
        const float rx = R[(size_t)(base + j) * 3 + 0];
        const float ry = R[(size_t)(base + j) * 3 + 1];
        const float rz = R[(size_t)(base + j) * 3 + 2];
        sref[j] = make_float4(rx, ry, rz, 0.5f * (rx * rx + ry * ry + rz * rz));
    }
    __syncthreads();
    const float qx = Q[q * 3 + 0], qy = Q[q * 3 + 1], qz = Q[q * 3 + 2];
    float best = 3.4e38f; int bestj = base;
    #pragma unroll 8
    for (int j = 0; j < 1024; ++j) {
        const float4 r = sref[j];
        float t = __fmaf_rn(-qx, r.x, r.w);
        t = __fmaf_rn(-qy, r.y, t);
        t = __fmaf_rn(-qz, r.z, t);
        const bool c = t < best;
        best = c ? t : best; bestj = c ? (base + j) : bestj;
    }
    const size_t idx = ((size_t)dir * 8 + b) * (size_t)N + q;
    atomicMin(&packed[idx], ((unsigned long long)float_ord(best) << 32) | (unsigned int)bestj);
}

__global__ __launch_bounds__(BQ) void chamfer_gather_kernel(
    const float* __restrict__ x, const float* __restrict__ y,
    const unsigned long long* __restrict__ packed,
    float* __restrict__ acc, int N, int M)
{
    __shared__ float red[4];
    const int tid = threadIdx.x;
    const size_t gq = (size_t)blockIdx.x * BQ + tid;
    const int dir = (int)(gq / ((size_t)8 * N));
    const size_t rem = gq - (size_t)dir * 8 * N;
    const int b = (int)(rem / N), q = (int)(rem - (size_t)b * N);
    const float* Q; const float* R;
    if (dir == 0) { Q = x + (size_t)b * N * 3; R = y + (size_t)b * M * 3; }
    else          { Q = y + (size_t)b * M * 3; R = x + (size_t)b * N * 3; }
    const int j = (int)(unsigned int)packed[gq];
    const float dx = Q[q * 3 + 0] - R[(size_t)j * 3 + 0];
    const float dy = Q[q * 3 + 1] - R[(size_t)j * 3 + 1];
    const float dz = Q[q * 3 + 2] - R[(size_t)j * 3 + 2];
    const float ax = fabsf(dx), ay = fabsf(dy), az = fabsf(dz);
    const float ax2 = ax * ax, ay2 = ay * ay, az2 = az * az;
    float s = ax2 * ax2 * ax + ay2 * ay2 * ay + az2 * az2 * az;
    #pragma unroll
    for (int off = 32; off > 0; off >>= 1) s += __shfl_down(s, off, 64);
    const int wid = tid >> 6, lane = tid & 63;
    if (lane == 0) red[wid] = s;
    __syncthreads();
    if (tid == 0) atomicAdd(&acc[b * 2 + dir], red[0] + red[1] + red[2] + red[3]);
}

__global__ void chamfer_finalize_kernel(const float* __restrict__ acc,
                                        float* __restrict__ out)
{
    if (threadIdx.x == 0 && blockIdx.x == 0) {
        float total = 0.0f;
        #pragma unroll
        for (int i = 0; i < 16; ++i) total += powf(acc[i], 0.2f);
        *out = total * 0.125f;
    }
}

extern "C" void kernel_launch(void* const* d_in, const int* in_sizes, int n_in,
                              void* d_out, int out_size, void* d_ws, size_t ws_size,
                              hipStream_t stream)
{
    const float* x = (const float*)d_in[0];
    const float* y = (const float*)d_in[1];
    float* out = (float*)d_out;
    const int N = in_sizes[0] / 24;  // B=8, C=3
    const int M = in_sizes[1] / 24;

    const size_t needed = WS_TBL + (1u << 20);  // table ends at 2MB

    if (N == 4096 && M == 4096 && ws_size >= needed) {
        unsigned char* ws = (unsigned char*)d_ws;
        unsigned long long* tab = (unsigned long long*)(ws + WS_TAB);
        unsigned int* tcnt = (unsigned int*)(ws + WS_TCNT);
        unsigned int* gcnt = (unsigned int*)(ws + WS_GCNT);
        const unsigned int* canary = (const unsigned int*)(ws + WS_CANARY);
        float* psum = (float*)(ws + WS_PSUM);
        chamfer_mktab<<<32768 / BQ, BQ, 0, stream>>>(x, y, (float4*)(ws + WS_TBL));
        chamfer_fused_r14<<<NTILE * SPLITS, BQ, 0, stream>>>(
            x, y, (const f32x4*)(ws + WS_TBL), tab, tcnt, gcnt, canary, psum, out);
    } else {
        // round-2 proven path
        unsigned char* ws = (unsigned char*)d_ws;
        float* acc = (float*)ws;
        unsigned long long* ptab = (unsigned long long*)(ws + 4096);
        const size_t nQ = (size_t)2 * 8 * N;
        hipMemsetAsync(acc, 0, 64, stream);
        hipMemsetAsync(ptab, 0xFF, nQ * 8, stream);
        chamfer_nn_split_kernel<<<(int)(nQ / BQ) * 4, BQ, 0, stream>>>(x, y, ptab, N, M);
        chamfer_gather_kernel<<<(int)(nQ / BQ), BQ, 0, stream>>>(x, y, ptab, acc, N, M);
        chamfer_finalize_kernel<<<1, 64, 0, stream>>>(acc, out);
    }
}